// Round 8
// baseline (199.118 us; speedup 1.0000x reference)
//
#include <hip/hip_runtime.h>

#define EPS 1e-3f
#define SLOPE 0.01f
#define TPW 4   // 16-point tiles per wave
#define NBANK 16  // stats atomic spread banks

typedef __attribute__((ext_vector_type(8))) short s8v;
typedef __attribute__((ext_vector_type(4))) float f4v;

union U4S8 {
  uint4 u;
  s8v s;
};

static __device__ inline unsigned f2bf(float x) {  // RNE f32->bf16 (low 16)
  unsigned u = __float_as_uint(x);
  return (u + 0x7fffu + ((u >> 16) & 1u)) >> 16;
}
static __device__ inline float bf_lo(unsigned u) {
  return __uint_as_float(u << 16);
}
static __device__ inline float bf_hi(unsigned u) {
  return __uint_as_float(u & 0xffff0000u);
}

// ---------------------------------------------------------------------------
// prep kernel: fused {feature f32->bf16 convert | sums/zero-row/ctr init |
// K1 B-fragment table build}. One dispatch replaces three tiny ones.
// ---------------------------------------------------------------------------
__global__ __launch_bounds__(256) void prep_kernel(
    const float* __restrict__ features, uint4* __restrict__ fbf, int n8,
    const float* __restrict__ w1, const float* __restrict__ w2,
    uint4* __restrict__ tab, float* __restrict__ sums, uint4* __restrict__ r0,
    uint4* __restrict__ r1, uint4* __restrict__ r2, unsigned* __restrict__ ctr,
    int nc) {
  const int b = blockIdx.x;
  const int tid = threadIdx.x;
  if (b < nc) {  // cvt: features f32 -> bf16 rows
    int i = b * 256 + tid;
    if (i < n8) {
      const float4* p = (const float4*)features + (size_t)i * 2;
      float4 a = p[0], bb = p[1];
      uint4 o;
      o.x = f2bf(a.x) | (f2bf(a.y) << 16);
      o.y = f2bf(a.z) | (f2bf(a.w) << 16);
      o.z = f2bf(bb.x) | (f2bf(bb.y) << 16);
      o.w = f2bf(bb.z) | (f2bf(bb.w) << 16);
      fbf[i] = o;
    }
  } else if (b == nc) {  // init: stats accumulators + zero rows + sync ctr
#pragma unroll
    for (int i = 0; i < 16; i++) sums[i * 256 + tid] = 0.f;
    uint4 z = {0u, 0u, 0u, 0u};
    if (tid < 2) r0[tid] = z;
    else if (tid < 6) r1[tid - 2] = z;
    else if (tid < 10) r2[tid - 6] = z;
    else if (tid == 10) *ctr = 0u;
  } else if (tid < 64) {  // build K1 tables (20 slot-blocks)
    const int sb = b - nc - 1;  // 0..19
    const int conv = sb / 10, slot = sb % 10;
    const float* w = conv ? w2 : w1;
    const int T = slot >> 1, f = slot & 1;
    const int g = tid >> 4, c = tid & 15;
    s8v t;
#pragma unroll
    for (int j = 0; j < 8; j++) {
      int kl = g * 8 + j;
      int tap = 2 * T + (kl >> 4);
      int ci = kl & 15;
      t[j] = (short)(tap < 9 ? f2bf(w[(tap * 16 + ci) * 32 + 2 * c + f]) : 0);
    }
    U4S8 u;
    u.s = t;
    tab[(conv * 10 + slot) * 64 + tid] = u.u;
  }
}

__global__ __launch_bounds__(64) void build_tab_k2(
    const float* __restrict__ w12, const float* __restrict__ w3,
    const float* __restrict__ sums1, const float* __restrict__ sums2,
    const float* __restrict__ g0, const float* __restrict__ b0,
    const float* __restrict__ g1, const float* __restrict__ b1,
    uint4* __restrict__ tab, int n) {
  __shared__ float stl[64];
  const int conv = blockIdx.x / 20, slot = blockIdx.x % 20;
  const float* w = conv ? w3 : w12;
  const float* sums = conv ? sums2 : sums1;
  const float* bn_g = conv ? g1 : g0;
  const float* bn_b = conv ? b1 : b0;
  const int lane = threadIdx.x;
  if (lane < 32) {
    float ssum = 0.f, qsum = 0.f;
#pragma unroll
    for (int bk = 0; bk < NBANK; bk++) {  // reduce spread banks
      ssum += sums[bk * 64 + lane];
      qsum += sums[bk * 64 + 32 + lane];
    }
    float inv_n = 1.0f / (float)n;
    float m = ssum * inv_n;
    float v = qsum * inv_n - m * m;
    float s = bn_g[lane] * rsqrtf(v + EPS);
    stl[lane] = s;
    stl[32 + lane] = bn_b[lane] - m * s;
  }
  __syncthreads();
  const int g = lane >> 4, c = lane & 15;
  s8v t;
  if (slot < 18) {
    const int k = slot >> 1, f = slot & 1;
#pragma unroll
    for (int j = 0; j < 8; j++) {
      int ci = g * 8 + j;
      t[j] = (short)f2bf(w[(k * 32 + ci) * 32 + 2 * c + f] * stl[ci]);
    }
  } else {
    const int f = slot - 18;
#pragma unroll
    for (int j = 0; j < 8; j++) {
      int kk = g * 8 + j;
      if (kk < 9) {
        float a = 0.f;
        for (int ci = 0; ci < 32; ci++)
          a += stl[32 + ci] * w[(kk * 32 + ci) * 32 + 2 * c + f];
        t[j] = (short)f2bf(a);
      } else {
        t[j] = 0;
      }
    }
  }
  U4S8 u;
  u.s = t;
  tab[(conv * 20 + slot) * 64 + lane] = u.u;
}

// ---------------------------------------------------------------------------
// K1 MFMA subm-conv (paired): R19 config (4 blk/CU; R20's 6 was neutral-worse).
// Per tile: idx load -> UNCONDITIONAL gathers (dead slots read maintained
// zero row n; static schedule => counted vmcnt) -> slot-skipped MFMAs.
// ---------------------------------------------------------------------------
__global__ __launch_bounds__(256, 4) void conv_mfma_k1(
    const unsigned short* __restrict__ src0, const int* __restrict__ nbr0,
    const uint4* __restrict__ tab0, unsigned short* __restrict__ dst0,
    float* __restrict__ osums0, const int* __restrict__ nbr1,
    const uint4* __restrict__ tab1, unsigned short* __restrict__ dst1,
    float* __restrict__ osums1, int n, int gb) {
  constexpr int NS = 5;
  __shared__ uint4 bwl[10 * 64];
  __shared__ float redl[4 * 64];

  const int tid = threadIdx.x;
  const bool second = (int)blockIdx.x >= gb;
  const unsigned short* src = src0;
  const int* nbr = second ? nbr1 : nbr0;
  const uint4* tab = second ? tab1 : tab0;
  unsigned short* dst = second ? dst1 : dst0;
  float* osums = second ? osums1 : osums0;

  for (int i = tid; i < 10 * 64; i += 256) bwl[i] = tab[i];
  __syncthreads();

  const int lane = tid & 63;
  const int wv = tid >> 6;
  const int g = lane >> 4;
  const int c = lane & 15;

  const int bid = second ? (int)blockIdx.x - gb : (int)blockIdx.x;
  const int wbase = bid * (64 * TPW) + wv * (16 * TPW);

  float s0 = 0.f, s1 = 0.f, q0 = 0.f, q1 = 0.f;

#pragma unroll 1
  for (int t = 0; t < TPW; t++) {
    const int pbase = wbase + t * 16;
    int jj[9];
    {
      int pt = pbase + c;
      bool a = pt < n;
#pragma unroll
      for (int k = 0; k < 9; k++) jj[k] = a ? nbr[(size_t)k * n + pt] : -1;
    }
    uint4 ga[NS];
#pragma unroll
    for (int s = 0; s < NS; s++) {
      int jA = jj[2 * s];
      int jB = jj[(2 * s + 1 < 9) ? 2 * s + 1 : 8];
      int jr = (g & 2) ? jB : jA;
      unsigned jc = jr < 0 ? (unsigned)n : (unsigned)jr;  // zero row
      ga[s] = ((const uint4*)src)[(size_t)jc * 2 + (g & 1)];
    }
    unsigned son = 0;
#pragma unroll
    for (int s = 0; s < NS; s++) {
      int jA = jj[2 * s];
      int jB = jj[(2 * s + 1 < 9) ? 2 * s + 1 : 8];
      bool on = __ballot(jA >= 0 || jB >= 0) != 0ull;
      son |= (on ? 1u : 0u) << s;
    }
    f4v acc0 = {0.f, 0.f, 0.f, 0.f};
    f4v acc1 = {0.f, 0.f, 0.f, 0.f};
#pragma unroll
    for (int s = 0; s < NS; s++) {
      if (son & (1u << s)) {
        U4S8 a;
        a.u = ga[s];
        U4S8 b0, b1;
        b0.u = bwl[(s * 2 + 0) * 64 + lane];
        b1.u = bwl[(s * 2 + 1) * 64 + lane];
        acc0 = __builtin_amdgcn_mfma_f32_16x16x32_bf16(a.s, b0.s, acc0, 0, 0, 0);
        acc1 = __builtin_amdgcn_mfma_f32_16x16x32_bf16(a.s, b1.s, acc1, 0, 0, 0);
      }
    }
#pragma unroll
    for (int r = 0; r < 4; r++) {
      float x = acc0[r];
      x = fmaxf(x, SLOPE * x);
      acc0[r] = x;
      s0 += x;
      q0 = fmaf(x, x, q0);
      float y = acc1[r];
      y = fmaxf(y, SLOPE * y);
      acc1[r] = y;
      s1 += y;
      q1 = fmaf(y, y, q1);
    }
#pragma unroll
    for (int r = 0; r < 4; r++) {
      int p = pbase + g * 4 + r;
      if (p < n)
        ((unsigned*)dst)[(size_t)p * 16 + c] =
            f2bf(acc0[r]) | (f2bf(acc1[r]) << 16);
    }
  }

  s0 += __shfl_xor(s0, 16, 64);
  s0 += __shfl_xor(s0, 32, 64);
  s1 += __shfl_xor(s1, 16, 64);
  s1 += __shfl_xor(s1, 32, 64);
  q0 += __shfl_xor(q0, 16, 64);
  q0 += __shfl_xor(q0, 32, 64);
  q1 += __shfl_xor(q1, 16, 64);
  q1 += __shfl_xor(q1, 32, 64);
  if (lane < 16) {
    redl[wv * 64 + 2 * c] = s0;
    redl[wv * 64 + 2 * c + 1] = s1;
    redl[wv * 64 + 32 + 2 * c] = q0;
    redl[wv * 64 + 32 + 2 * c + 1] = q1;
  }
  __syncthreads();
  if (tid < 64) {
    float t = redl[tid] + redl[64 + tid] + redl[128 + tid] + redl[192 + tid];
    atomicAdd(&osums[(bid & (NBANK - 1)) * 64 + tid], t);
  }
}

// ---------------------------------------------------------------------------
// R21: fused K2 + final. Each block does BOTH K2 convs for the SAME 256
// points (tables staged sequentially, 21.5KB LDS -> 4 blk/CU = 86KB OK),
// stores z12/z3 to global (fire-and-forget), proven R16 atomic handoff,
// then re-reads its OWN z slices (own-CU L1 / own-XCD L2 hits -- no
// cross-XCD visibility needed) and writes out. vs R16: occupancy 4 blk/CU
// (not 2) -- grid 977 <= 4x256=1024 co-resident; no zheld (VGPR stays at
// R19-K2 level under the 128 cap). Eliminates final_kernel's 32MB cold
// z-read + dispatch + gap.
// ---------------------------------------------------------------------------
__global__ __launch_bounds__(256, 4) void conv_k2_fused(
    const unsigned short* __restrict__ srcA, const int* __restrict__ nbrA,
    const unsigned short* __restrict__ srcB, const int* __restrict__ nbrB,
    const uint4* __restrict__ tab, unsigned short* __restrict__ z12,
    unsigned short* __restrict__ z3, float* __restrict__ sumsA,
    float* __restrict__ sumsB, const float* __restrict__ gA,
    const float* __restrict__ bA, const float* __restrict__ gB,
    const float* __restrict__ bB, float* __restrict__ out,
    unsigned* __restrict__ ctr, int n) {
  __shared__ uint4 bwl[20 * 64];
  __shared__ float redl[4 * 64];
  __shared__ float st[128];

  const int tid = threadIdx.x;
  const int lane = tid & 63;
  const int wv = tid >> 6;
  const int g = lane >> 4;
  const int c = lane & 15;
  const int bid = (int)blockIdx.x;
  const int wbase = bid * 256 + wv * (16 * TPW);

#pragma unroll 1
  for (int conv = 0; conv < 2; conv++) {
    const unsigned short* src = conv ? srcB : srcA;
    const int* nbr = conv ? nbrB : nbrA;
    unsigned short* dst = conv ? z3 : z12;
    float* osums = conv ? sumsB : sumsA;

    __syncthreads();  // prior conv's bwl readers done before restage
    for (int i = tid; i < 20 * 64; i += 256) bwl[i] = tab[conv * 20 * 64 + i];
    __syncthreads();

    s8v bbias0, bbias1;
    {
      U4S8 x;
      x.u = bwl[18 * 64 + lane];
      bbias0 = x.s;
      x.u = bwl[19 * 64 + lane];
      bbias1 = x.s;
    }

    float s0 = 0.f, s1 = 0.f, q0 = 0.f, q1 = 0.f;

#pragma unroll 1
    for (int t = 0; t < TPW; t++) {
      const int pbase = wbase + t * 16;
      int jj[9];
      {
        int pt = pbase + c;
        bool a = pt < n;
#pragma unroll
        for (int k = 0; k < 9; k++) jj[k] = a ? nbr[(size_t)k * n + pt] : -1;
      }
      uint4 ga[9];
#pragma unroll
      for (int s = 0; s < 9; s++) {
        unsigned jc = jj[s] < 0 ? (unsigned)n : (unsigned)jj[s];  // zero row
        ga[s] = ((const uint4*)src)[(size_t)jc * 4 + g];
      }
      unsigned vmask = 0;
#pragma unroll
      for (int k = 0; k < 9; k++) vmask |= (jj[k] >= 0 ? 1u : 0u) << k;
      unsigned son = 0;
#pragma unroll
      for (int s = 0; s < 9; s++) {
        bool on = __ballot(jj[s] >= 0) != 0ull;
        son |= (on ? 1u : 0u) << s;
      }

      f4v acc0 = {0.f, 0.f, 0.f, 0.f};
      f4v acc1 = {0.f, 0.f, 0.f, 0.f};
#pragma unroll
      for (int s = 0; s < 9; s++) {
        if (son & (1u << s)) {
          U4S8 a;
          a.u = ga[s];
          U4S8 b0, b1;
          b0.u = bwl[(s * 2 + 0) * 64 + lane];
          b1.u = bwl[(s * 2 + 1) * 64 + lane];
          acc0 =
              __builtin_amdgcn_mfma_f32_16x16x32_bf16(a.s, b0.s, acc0, 0, 0, 0);
          acc1 =
              __builtin_amdgcn_mfma_f32_16x16x32_bf16(a.s, b1.s, acc1, 0, 0, 0);
        }
      }
      {  // bias via validity-matrix MFMA
        s8v av;
#pragma unroll
        for (int j = 0; j < 8; j++) {
          unsigned kk = (unsigned)(g * 8 + j);
          unsigned bit = (kk < 32u) ? ((vmask >> kk) & 1u) : 0u;
          av[j] = (short)(bit ? 0x3F80 : 0);
        }
        acc0 =
            __builtin_amdgcn_mfma_f32_16x16x32_bf16(av, bbias0, acc0, 0, 0, 0);
        acc1 =
            __builtin_amdgcn_mfma_f32_16x16x32_bf16(av, bbias1, acc1, 0, 0, 0);
      }

#pragma unroll
      for (int r = 0; r < 4; r++) {
        float x = acc0[r];
        x = fmaxf(x, SLOPE * x);
        acc0[r] = x;
        s0 += x;
        q0 = fmaf(x, x, q0);
        float y = acc1[r];
        y = fmaxf(y, SLOPE * y);
        acc1[r] = y;
        s1 += y;
        q1 = fmaf(y, y, q1);
      }
#pragma unroll
      for (int r = 0; r < 4; r++) {
        int p = pbase + g * 4 + r;
        if (p < n)
          ((unsigned*)dst)[(size_t)p * 16 + c] =
              f2bf(acc0[r]) | (f2bf(acc1[r]) << 16);
      }
    }

    s0 += __shfl_xor(s0, 16, 64);
    s0 += __shfl_xor(s0, 32, 64);
    s1 += __shfl_xor(s1, 16, 64);
    s1 += __shfl_xor(s1, 32, 64);
    q0 += __shfl_xor(q0, 16, 64);
    q0 += __shfl_xor(q0, 32, 64);
    q1 += __shfl_xor(q1, 16, 64);
    q1 += __shfl_xor(q1, 32, 64);
    __syncthreads();
    if (lane < 16) {
      redl[wv * 64 + 2 * c] = s0;
      redl[wv * 64 + 2 * c + 1] = s1;
      redl[wv * 64 + 32 + 2 * c] = q0;
      redl[wv * 64 + 32 + 2 * c + 1] = q1;
    }
    __syncthreads();
    if (tid < 64) {
      float t = redl[tid] + redl[64 + tid] + redl[128 + tid] + redl[192 + tid];
      atomicAdd(&osums[(bid & (NBANK - 1)) * 64 + tid], t);
    }
  }

  // ---- proven grid handoff (R16): release atomics, wait for all blocks ----
  __syncthreads();
  if (tid == 0) {
    __hip_atomic_fetch_add(ctr, 1u, __ATOMIC_ACQ_REL, __HIP_MEMORY_SCOPE_AGENT);
    while (__hip_atomic_load(ctr, __ATOMIC_ACQUIRE, __HIP_MEMORY_SCOPE_AGENT) <
           gridDim.x)
      __builtin_amdgcn_s_sleep(2);
  }
  __syncthreads();

  if (tid < 32) {
    float sa = 0.f, qa = 0.f, sb = 0.f, qb = 0.f;
#pragma unroll
    for (int bk = 0; bk < NBANK; bk++) {  // agent-scope atomic loads: fresh
      sa += __hip_atomic_load(&sumsA[bk * 64 + tid], __ATOMIC_RELAXED,
                              __HIP_MEMORY_SCOPE_AGENT);
      qa += __hip_atomic_load(&sumsA[bk * 64 + 32 + tid], __ATOMIC_RELAXED,
                              __HIP_MEMORY_SCOPE_AGENT);
      sb += __hip_atomic_load(&sumsB[bk * 64 + tid], __ATOMIC_RELAXED,
                              __HIP_MEMORY_SCOPE_AGENT);
      qb += __hip_atomic_load(&sumsB[bk * 64 + 32 + tid], __ATOMIC_RELAXED,
                              __HIP_MEMORY_SCOPE_AGENT);
    }
    float inv_n = 1.0f / (float)n;
    float m = sa * inv_n;
    float v = qa * inv_n - m * m;
    float s = gA[tid] * rsqrtf(v + EPS);
    st[tid] = s;
    st[32 + tid] = bA[tid] - m * s;
    m = sb * inv_n;
    v = qb * inv_n - m * m;
    s = gB[tid] * rsqrtf(v + EPS);
    st[64 + tid] = s;
    st[96 + tid] = bB[tid] - m * s;
  }
  __syncthreads();

  // ---- epilogue: re-read OWN 256-point z slices (L1/L2-hot), write out ----
#pragma unroll 1
  for (int it = 0; it < 4; it++) {
    int idx = it * 256 + tid;       // block-local chunk id, 1024 total
    int p = bid * 256 + (idx >> 2); // point
    if (p < n) {
      int ch = idx & 3;             // 8-channel chunk within point
      int c0 = ch * 8;
      uint4 a = ((const uint4*)z12)[(size_t)p * 4 + ch];
      uint4 b = ((const uint4*)z3)[(size_t)p * 4 + ch];
      float4 r0, r1;
      r0.x = bf_lo(a.x) * st[c0 + 0] + st[32 + c0 + 0] + bf_lo(b.x) * st[64 + c0 + 0] + st[96 + c0 + 0];
      r0.y = bf_hi(a.x) * st[c0 + 1] + st[32 + c0 + 1] + bf_hi(b.x) * st[64 + c0 + 1] + st[96 + c0 + 1];
      r0.z = bf_lo(a.y) * st[c0 + 2] + st[32 + c0 + 2] + bf_lo(b.y) * st[64 + c0 + 2] + st[96 + c0 + 2];
      r0.w = bf_hi(a.y) * st[c0 + 3] + st[32 + c0 + 3] + bf_hi(b.y) * st[64 + c0 + 3] + st[96 + c0 + 3];
      r1.x = bf_lo(a.z) * st[c0 + 4] + st[32 + c0 + 4] + bf_lo(b.z) * st[64 + c0 + 4] + st[96 + c0 + 4];
      r1.y = bf_hi(a.z) * st[c0 + 5] + st[32 + c0 + 5] + bf_hi(b.z) * st[64 + c0 + 5] + st[96 + c0 + 5];
      r1.z = bf_lo(a.w) * st[c0 + 6] + st[32 + c0 + 6] + bf_lo(b.w) * st[64 + c0 + 6] + st[96 + c0 + 6];
      r1.w = bf_hi(a.w) * st[c0 + 7] + st[32 + c0 + 7] + bf_hi(b.w) * st[64 + c0 + 7] + st[96 + c0 + 7];
      size_t o = ((size_t)p * 4 + ch) * 2;
      ((float4*)out)[o + 0] = r0;
      ((float4*)out)[o + 1] = r1;
    }
  }
}

extern "C" void kernel_launch(void* const* d_in, const int* in_sizes, int n_in,
                              void* d_out, int out_size, void* d_ws,
                              size_t ws_size, hipStream_t stream) {
  const float* features = (const float*)d_in[0];
  const int* nbr133 = (const int*)d_in[1];
  const int* nbr313 = (const int*)d_in[2];
  const float* conv1_w = (const float*)d_in[3];
  const float* conv12_w = (const float*)d_in[4];
  const float* conv2_w = (const float*)d_in[5];
  const float* conv3_w = (const float*)d_in[6];
  const float* bn0_g = (const float*)d_in[7];
  const float* bn0_b = (const float*)d_in[8];
  const float* bn02_g = (const float*)d_in[9];
  const float* bn02_b = (const float*)d_in[10];
  const float* bn1_g = (const float*)d_in[11];
  const float* bn1_b = (const float*)d_in[12];
  const float* bn2_g = (const float*)d_in[13];
  const float* bn2_b = (const float*)d_in[14];
  float* out = (float*)d_out;

  const int n = in_sizes[0] / 16;  // 250000
  char* ws = (char*)d_ws;
  const size_t A = (size_t)n * 64 + 64;  // bf16 [n+1][32] region

  // region0: fbf ([n+1][16] bf16) overlaid later by z12 ([n][32] bf16)
  unsigned short* fbf = (unsigned short*)ws;
  unsigned short* z12 = (unsigned short*)ws;
  unsigned short* zA1 = (unsigned short*)(ws + A);
  unsigned short* zA2 = (unsigned short*)(ws + 2 * A);
  unsigned short* z3 = (unsigned short*)(ws + 3 * A);
  float* sums = (float*)(ws + 4 * A);
  // sums: 4 stat sets x NBANK banks x 64 floats:
  //   +0 z1 | +1024 z2 | +2048 z12 | +3072 z3
  uint4* tabK1 = (uint4*)(ws + 4 * A + 4 * NBANK * 64 * 4);
  uint4* tabK2 = tabK1 + 20 * 64;
  unsigned* ctr = (unsigned*)(tabK2 + 40 * 64);

  const int n8 = n * 2;  // 8-float chunks of features
  const int nc = (n8 + 255) / 256;
  // fused prep: cvt | init | tabK1 build
  prep_kernel<<<nc + 21, 256, 0, stream>>>(
      features, (uint4*)fbf, n8, conv1_w, conv2_w, tabK1, sums,
      (uint4*)(ws + (size_t)n * 32),            // fbf row n
      (uint4*)(ws + A + (size_t)n * 64),        // zA1 row n
      (uint4*)(ws + 2 * A + (size_t)n * 64),    // zA2 row n
      ctr, nc);

  const int gb = (n + 64 * TPW - 1) / (64 * TPW);
  // K1: conv1 (fbf,nbr133)->zA1 || conv2 (fbf,nbr313)->zA2 (shared src)
  conv_mfma_k1<<<2 * gb, 256, 0, stream>>>(fbf, nbr133, tabK1, zA1, sums + 0,
                                           nbr313, tabK1 + 10 * 64, zA2,
                                           sums + 1024, n, gb);
  // tables for K2 (BN of K1 folded in; needs K1 stats)
  build_tab_k2<<<40, 64, 0, stream>>>(conv12_w, conv3_w, sums + 0, sums + 1024,
                                      bn0_g, bn0_b, bn1_g, bn1_b, tabK2, n);
  // fused K2+final: conv12 (bn0(zA1),nbr313)->z12 AND conv3 (bn1(zA2),
  // nbr133)->z3 per block, handoff, out = bn02(z12)+bn2(z3).
  // grid 977 co-resident at 4 blk/CU (launch_bounds(256,4), LDS 21.5KB).
  const int gb2 = (n + 255) / 256;
  conv_k2_fused<<<gb2, 256, 0, stream>>>(
      zA1, nbr313, zA2, nbr133, tabK2, z12, z3, sums + 2048, sums + 3072,
      bn02_g, bn02_b, bn2_g, bn2_b, out, ctr, n);
}

// Round 9
// 70.363 us; speedup vs baseline: 2.8299x; 2.8299x over previous
//
#include <hip/hip_runtime.h>

#define EPS 1e-3f
#define SLOPE 0.01f
#define NBANK 16  // stats atomic spread banks

typedef __attribute__((ext_vector_type(8))) short s8v;
typedef __attribute__((ext_vector_type(4))) float f4v;

union U4S8 {
  uint4 u;
  s8v s;
};

static __device__ inline unsigned f2bf(float x) {  // RNE f32->bf16 (low 16)
  unsigned u = __float_as_uint(x);
  return (u + 0x7fffu + ((u >> 16) & 1u)) >> 16;
}
static __device__ inline float bf_lo(unsigned u) {
  return __uint_as_float(u << 16);
}
static __device__ inline float bf_hi(unsigned u) {
  return __uint_as_float(u & 0xffff0000u);
}

// ---------------------------------------------------------------------------
// prep kernel: fused {feature f32->bf16 convert | sums/zero-row init |
// K1 B-fragment table build}. One dispatch replaces three tiny ones.
// ---------------------------------------------------------------------------
__global__ __launch_bounds__(256) void prep_kernel(
    const float* __restrict__ features, uint4* __restrict__ fbf, int n8,
    const float* __restrict__ w1, const float* __restrict__ w2,
    uint4* __restrict__ tab, float* __restrict__ sums, uint4* __restrict__ r0,
    uint4* __restrict__ r1, uint4* __restrict__ r2, int nc) {
  const int b = blockIdx.x;
  const int tid = threadIdx.x;
  if (b < nc) {  // cvt: features f32 -> bf16 rows
    int i = b * 256 + tid;
    if (i < n8) {
      const float4* p = (const float4*)features + (size_t)i * 2;
      float4 a = p[0], bb = p[1];
      uint4 o;
      o.x = f2bf(a.x) | (f2bf(a.y) << 16);
      o.y = f2bf(a.z) | (f2bf(a.w) << 16);
      o.z = f2bf(bb.x) | (f2bf(bb.y) << 16);
      o.w = f2bf(bb.z) | (f2bf(bb.w) << 16);
      fbf[i] = o;
    }
  } else if (b == nc) {  // init: stats accumulators + zero rows
#pragma unroll
    for (int i = 0; i < 16; i++) sums[i * 256 + tid] = 0.f;
    uint4 z = {0u, 0u, 0u, 0u};
    if (tid < 2) r0[tid] = z;
    else if (tid < 6) r1[tid - 2] = z;
    else if (tid < 10) r2[tid - 6] = z;
  } else if (tid < 64) {  // build K1 tables (20 slot-blocks)
    const int sb = b - nc - 1;  // 0..19
    const int conv = sb / 10, slot = sb % 10;
    const float* w = conv ? w2 : w1;
    const int T = slot >> 1, f = slot & 1;
    const int g = tid >> 4, c = tid & 15;
    s8v t;
#pragma unroll
    for (int j = 0; j < 8; j++) {
      int kl = g * 8 + j;
      int tap = 2 * T + (kl >> 4);
      int ci = kl & 15;
      t[j] = (short)(tap < 9 ? f2bf(w[(tap * 16 + ci) * 32 + 2 * c + f]) : 0);
    }
    U4S8 u;
    u.s = t;
    tab[(conv * 10 + slot) * 64 + tid] = u.u;
  }
}

__global__ __launch_bounds__(64) void build_tab_k2(
    const float* __restrict__ w12, const float* __restrict__ w3,
    const float* __restrict__ sums1, const float* __restrict__ sums2,
    const float* __restrict__ g0, const float* __restrict__ b0,
    const float* __restrict__ g1, const float* __restrict__ b1,
    uint4* __restrict__ tab, int n) {
  __shared__ float stl[64];
  const int conv = blockIdx.x / 20, slot = blockIdx.x % 20;
  const float* w = conv ? w3 : w12;
  const float* sums = conv ? sums2 : sums1;
  const float* bn_g = conv ? g1 : g0;
  const float* bn_b = conv ? b1 : b0;
  const int lane = threadIdx.x;
  if (lane < 32) {
    float ssum = 0.f, qsum = 0.f;
#pragma unroll
    for (int bk = 0; bk < NBANK; bk++) {  // reduce spread banks
      ssum += sums[bk * 64 + lane];
      qsum += sums[bk * 64 + 32 + lane];
    }
    float inv_n = 1.0f / (float)n;
    float m = ssum * inv_n;
    float v = qsum * inv_n - m * m;
    float s = bn_g[lane] * rsqrtf(v + EPS);
    stl[lane] = s;
    stl[32 + lane] = bn_b[lane] - m * s;
  }
  __syncthreads();
  const int g = lane >> 4, c = lane & 15;
  s8v t;
  if (slot < 18) {
    const int k = slot >> 1, f = slot & 1;
#pragma unroll
    for (int j = 0; j < 8; j++) {
      int ci = g * 8 + j;
      t[j] = (short)f2bf(w[(k * 32 + ci) * 32 + 2 * c + f] * stl[ci]);
    }
  } else {
    const int f = slot - 18;
#pragma unroll
    for (int j = 0; j < 8; j++) {
      int kk = g * 8 + j;
      if (kk < 9) {
        float a = 0.f;
        for (int ci = 0; ci < 32; ci++)
          a += stl[32 + ci] * w[(kk * 32 + ci) * 32 + 2 * c + f];
        t[j] = (short)f2bf(a);
      } else {
        t[j] = 0;
      }
    }
  }
  U4S8 u;
  u.s = t;
  tab[(conv * 20 + slot) * 64 + lane] = u.u;
}

// ---------------------------------------------------------------------------
// MFMA subm-conv, R22: exact R19 structure (verified 71.55us best), TPW
// templated. R21 post-mortem: fusing final into K2 made the register
// allocator drop to 48 VGPR and serialize the 9 gathers (5x per-wave
// slowdown at same occupancy) -- fusion abandoned; separate kernels keep
// the compiler's MLP-friendly allocation (~100 VGPR, 9 loads in flight).
// Delta vs R19: K2 runs TPW=8 (half the blocks -> half the 21.5KB table
// stagings and block prologues; same VGPR/LDS/occupancy). K1 stays TPW=4.
// Per tile: idx load -> UNCONDITIONAL gathers (dead slots read maintained
// zero row n; static schedule => counted vmcnt) -> slot-skipped MFMAs.
// ---------------------------------------------------------------------------
template <bool PAIRED, int TPWK>
__global__ __launch_bounds__(256, 4) void conv_mfma(
    const unsigned short* __restrict__ src0, const int* __restrict__ nbr0,
    const uint4* __restrict__ tab0, unsigned short* __restrict__ dst0,
    float* __restrict__ osums0, const unsigned short* __restrict__ src1,
    const int* __restrict__ nbr1, const uint4* __restrict__ tab1,
    unsigned short* __restrict__ dst1, float* __restrict__ osums1, int n,
    int gb) {
  constexpr int NS = PAIRED ? 5 : 9;      // mfma slots per tile
  constexpr int NSLOT = PAIRED ? 10 : 20; // table slots
  __shared__ uint4 bwl[NSLOT * 64];
  __shared__ float redl[4 * 64];

  const int tid = threadIdx.x;
  const bool second = (int)blockIdx.x >= gb;
  const unsigned short* src = second ? src1 : src0;
  const int* nbr = second ? nbr1 : nbr0;
  const uint4* tab = second ? tab1 : tab0;
  unsigned short* dst = second ? dst1 : dst0;
  float* osums = second ? osums1 : osums0;

  // stage table global -> LDS (coalesced)
  for (int i = tid; i < NSLOT * 64; i += 256) bwl[i] = tab[i];
  __syncthreads();

  const int lane = tid & 63;
  const int wv = tid >> 6;
  const int g = lane >> 4;  // k-chunk group 0..3
  const int c = lane & 15;  // A row (point) / B col index (cout pair c)

  s8v bbias0, bbias1;
  if (!PAIRED) {
    U4S8 x;
    x.u = bwl[18 * 64 + lane];
    bbias0 = x.s;
    x.u = bwl[19 * 64 + lane];
    bbias1 = x.s;
  }

  const int bid = second ? (int)blockIdx.x - gb : (int)blockIdx.x;
  const int wbase = bid * (64 * TPWK) + wv * (16 * TPWK);

  float s0 = 0.f, s1 = 0.f, q0 = 0.f, q1 = 0.f;  // stats accumulators

#pragma unroll 1
  for (int t = 0; t < TPWK; t++) {
    const int pbase = wbase + t * 16;

    // ---- tile indices (coalesced; per-lane point pbase+c) ----
    int jj[9];
    {
      int pt = pbase + c;
      bool a = pt < n;
#pragma unroll
      for (int k = 0; k < 9; k++) jj[k] = a ? nbr[(size_t)k * n + pt] : -1;
    }

    // ---- UNCONDITIONAL gathers (dead lanes read zero row n: L1-hot line,
    //      broadcast within c-group; static schedule => counted vmcnt) ----
    uint4 ga[NS];
#pragma unroll
    for (int s = 0; s < NS; s++) {
      int jr;
      if (PAIRED) {
        int jA = jj[2 * s];
        int jB = jj[(2 * s + 1 < 9) ? 2 * s + 1 : 8];
        jr = (g & 2) ? jB : jA;
      } else {
        jr = jj[s];
      }
      unsigned jc = jr < 0 ? (unsigned)n : (unsigned)jr;  // zero row
      ga[s] = ((const uint4*)src)[PAIRED ? ((size_t)jc * 2 + (g & 1))
                                         : ((size_t)jc * 4 + g)];
    }

    // ---- per-slot wave-uniform validity (ballot -> scalar MFMA skip) ----
    unsigned vmask = 0;
    if (!PAIRED) {
#pragma unroll
      for (int k = 0; k < 9; k++) vmask |= (jj[k] >= 0 ? 1u : 0u) << k;
    }
    unsigned son = 0;
#pragma unroll
    for (int s = 0; s < NS; s++) {
      bool on;
      if (PAIRED) {
        int jA = jj[2 * s];
        int jB = jj[(2 * s + 1 < 9) ? 2 * s + 1 : 8];
        on = __ballot(jA >= 0 || jB >= 0) != 0ull;
      } else {
        on = __ballot(jj[s] >= 0) != 0ull;
      }
      son |= (on ? 1u : 0u) << s;
    }

    // ---- MFMA accumulate (live slots only) ----
    f4v acc0 = {0.f, 0.f, 0.f, 0.f};
    f4v acc1 = {0.f, 0.f, 0.f, 0.f};
#pragma unroll
    for (int s = 0; s < NS; s++) {
      if (son & (1u << s)) {  // wave-uniform scalar branch
        U4S8 a;
        a.u = ga[s];
        U4S8 b0, b1;
        b0.u = bwl[(s * 2 + 0) * 64 + lane];
        b1.u = bwl[(s * 2 + 1) * 64 + lane];
        acc0 = __builtin_amdgcn_mfma_f32_16x16x32_bf16(a.s, b0.s, acc0, 0, 0, 0);
        acc1 = __builtin_amdgcn_mfma_f32_16x16x32_bf16(a.s, b1.s, acc1, 0, 0, 0);
      }
    }
    if (!PAIRED) {  // bias via validity-matrix MFMA (covers all taps)
      s8v av;
#pragma unroll
      for (int j = 0; j < 8; j++) {
        unsigned kk = (unsigned)(g * 8 + j);
        unsigned bit = (kk < 32u) ? ((vmask >> kk) & 1u) : 0u;
        av[j] = (short)(bit ? 0x3F80 : 0);
      }
      acc0 = __builtin_amdgcn_mfma_f32_16x16x32_bf16(av, bbias0, acc0, 0, 0, 0);
      acc1 = __builtin_amdgcn_mfma_f32_16x16x32_bf16(av, bbias1, acc1, 0, 0, 0);
    }

    // ---- lrelu + stats ----
#pragma unroll
    for (int r = 0; r < 4; r++) {
      float x = acc0[r];
      x = fmaxf(x, SLOPE * x);
      acc0[r] = x;
      s0 += x;
      q0 = fmaf(x, x, q0);
      float y = acc1[r];
      y = fmaxf(y, SLOPE * y);
      acc1[r] = y;
      s1 += y;
      q1 = fmaf(y, y, q1);
    }

    // ---- direct coalesced store: lane (g,c) owns points pbase+g*4+r,
    //      couts (2c,2c+1) -> one packed bf16x2 dword each ----
#pragma unroll
    for (int r = 0; r < 4; r++) {
      int p = pbase + g * 4 + r;
      if (p < n)
        ((unsigned*)dst)[(size_t)p * 16 + c] =
            f2bf(acc0[r]) | (f2bf(acc1[r]) << 16);
    }
  }

  // ---- block stats reduction, one atomic per channel into spread bank ----
  s0 += __shfl_xor(s0, 16, 64);
  s0 += __shfl_xor(s0, 32, 64);
  s1 += __shfl_xor(s1, 16, 64);
  s1 += __shfl_xor(s1, 32, 64);
  q0 += __shfl_xor(q0, 16, 64);
  q0 += __shfl_xor(q0, 32, 64);
  q1 += __shfl_xor(q1, 16, 64);
  q1 += __shfl_xor(q1, 32, 64);
  if (lane < 16) {
    redl[wv * 64 + 2 * c] = s0;
    redl[wv * 64 + 2 * c + 1] = s1;
    redl[wv * 64 + 32 + 2 * c] = q0;
    redl[wv * 64 + 32 + 2 * c + 1] = q1;
  }
  __syncthreads();
  if (tid < 64) {
    float t = redl[tid] + redl[64 + tid] + redl[128 + tid] + redl[192 + tid];
    atomicAdd(&osums[(bid & (NBANK - 1)) * 64 + tid], t);
  }
}

// out = bnA(z12) + bnB(z3), both inputs bf16 [n][32]; sums are NBANK-spread
__global__ __launch_bounds__(256) void final_kernel(
    const uint4* __restrict__ z12, const uint4* __restrict__ z3,
    float* __restrict__ out, const float* __restrict__ sumsA,
    const float* __restrict__ gA, const float* __restrict__ bA,
    const float* __restrict__ sumsB, const float* __restrict__ gB,
    const float* __restrict__ bB, int n) {
  __shared__ float st[128];  // sA tA sB tB
  const int tid = threadIdx.x;
  if (tid < 32) {
    float sa = 0.f, qa = 0.f, sb = 0.f, qb = 0.f;
#pragma unroll
    for (int bk = 0; bk < NBANK; bk++) {
      sa += sumsA[bk * 64 + tid];
      qa += sumsA[bk * 64 + 32 + tid];
      sb += sumsB[bk * 64 + tid];
      qb += sumsB[bk * 64 + 32 + tid];
    }
    float inv_n = 1.0f / (float)n;
    float m = sa * inv_n;
    float v = qa * inv_n - m * m;
    float s = gA[tid] * rsqrtf(v + EPS);
    st[tid] = s;
    st[32 + tid] = bA[tid] - m * s;
    m = sb * inv_n;
    v = qb * inv_n - m * m;
    s = gB[tid] * rsqrtf(v + EPS);
    st[64 + tid] = s;
    st[96 + tid] = bB[tid] - m * s;
  }
  __syncthreads();
  const int total = n * 4;  // 8-channel chunks
  for (int i = blockIdx.x * 256 + tid; i < total; i += gridDim.x * 256) {
    int c0 = (i & 3) * 8;
    uint4 a = z12[i], b = z3[i];
    float4 r0, r1;
    r0.x = bf_lo(a.x) * st[c0 + 0] + st[32 + c0 + 0] + bf_lo(b.x) * st[64 + c0 + 0] + st[96 + c0 + 0];
    r0.y = bf_hi(a.x) * st[c0 + 1] + st[32 + c0 + 1] + bf_hi(b.x) * st[64 + c0 + 1] + st[96 + c0 + 1];
    r0.z = bf_lo(a.y) * st[c0 + 2] + st[32 + c0 + 2] + bf_lo(b.y) * st[64 + c0 + 2] + st[96 + c0 + 2];
    r0.w = bf_hi(a.y) * st[c0 + 3] + st[32 + c0 + 3] + bf_hi(b.y) * st[64 + c0 + 3] + st[96 + c0 + 3];
    r1.x = bf_lo(a.z) * st[c0 + 4] + st[32 + c0 + 4] + bf_lo(b.z) * st[64 + c0 + 4] + st[96 + c0 + 4];
    r1.y = bf_hi(a.z) * st[c0 + 5] + st[32 + c0 + 5] + bf_hi(b.z) * st[64 + c0 + 5] + st[96 + c0 + 5];
    r1.z = bf_lo(a.w) * st[c0 + 6] + st[32 + c0 + 6] + bf_lo(b.w) * st[64 + c0 + 6] + st[96 + c0 + 6];
    r1.w = bf_hi(a.w) * st[c0 + 7] + st[32 + c0 + 7] + bf_hi(b.w) * st[64 + c0 + 7] + st[96 + c0 + 7];
    ((float4*)out)[2 * i + 0] = r0;
    ((float4*)out)[2 * i + 1] = r1;
  }
}

extern "C" void kernel_launch(void* const* d_in, const int* in_sizes, int n_in,
                              void* d_out, int out_size, void* d_ws,
                              size_t ws_size, hipStream_t stream) {
  const float* features = (const float*)d_in[0];
  const int* nbr133 = (const int*)d_in[1];
  const int* nbr313 = (const int*)d_in[2];
  const float* conv1_w = (const float*)d_in[3];
  const float* conv12_w = (const float*)d_in[4];
  const float* conv2_w = (const float*)d_in[5];
  const float* conv3_w = (const float*)d_in[6];
  const float* bn0_g = (const float*)d_in[7];
  const float* bn0_b = (const float*)d_in[8];
  const float* bn02_g = (const float*)d_in[9];
  const float* bn02_b = (const float*)d_in[10];
  const float* bn1_g = (const float*)d_in[11];
  const float* bn1_b = (const float*)d_in[12];
  const float* bn2_g = (const float*)d_in[13];
  const float* bn2_b = (const float*)d_in[14];
  float* out = (float*)d_out;

  const int n = in_sizes[0] / 16;  // 250000
  char* ws = (char*)d_ws;
  const size_t A = (size_t)n * 64 + 64;  // bf16 [n+1][32] region

  // region0: fbf ([n+1][16] bf16) overlaid later by z12 ([n][32] bf16)
  unsigned short* fbf = (unsigned short*)ws;
  unsigned short* z12 = (unsigned short*)ws;
  unsigned short* zA1 = (unsigned short*)(ws + A);
  unsigned short* zA2 = (unsigned short*)(ws + 2 * A);
  unsigned short* z3 = (unsigned short*)(ws + 3 * A);
  float* sums = (float*)(ws + 4 * A);
  // sums: 4 stat sets x NBANK banks x 64 floats:
  //   +0 z1 | +1024 z2 | +2048 z12 | +3072 z3
  uint4* tabK1 = (uint4*)(ws + 4 * A + 4 * NBANK * 64 * 4);
  uint4* tabK2 = tabK1 + 20 * 64;

  const int n8 = n * 2;  // 8-float chunks of features
  const int nc = (n8 + 255) / 256;
  // fused prep: cvt | init | tabK1 build
  prep_kernel<<<nc + 21, 256, 0, stream>>>(
      features, (uint4*)fbf, n8, conv1_w, conv2_w, tabK1, sums,
      (uint4*)(ws + (size_t)n * 32),            // fbf row n
      (uint4*)(ws + A + (size_t)n * 64),        // zA1 row n
      (uint4*)(ws + 2 * A + (size_t)n * 64),    // zA2 row n
      nc);

  const int gb1 = (n + 255) / 256;  // K1: TPW=4, 256 pts/block
  // K1: conv1 (fbf,nbr133)->zA1 || conv2 (fbf,nbr313)->zA2
  conv_mfma<true, 4><<<2 * gb1, 256, 0, stream>>>(
      fbf, nbr133, tabK1, zA1, sums + 0, fbf, nbr313, tabK1 + 10 * 64, zA2,
      sums + 1024, n, gb1);
  // tables for K2 (BN of K1 folded in; needs K1 stats)
  build_tab_k2<<<40, 64, 0, stream>>>(conv12_w, conv3_w, sums + 0, sums + 1024,
                                      bn0_g, bn0_b, bn1_g, bn1_b, tabK2, n);
  const int gb2 = (n + 511) / 512;  // K2: TPW=8, 512 pts/block
  // K2: conv12 (bn0(zA1),nbr313)->z12 || conv3 (bn1(zA2),nbr133)->z3
  conv_mfma<false, 8><<<2 * gb2, 256, 0, stream>>>(
      zA1, nbr313, tabK2, z12, sums + 2048, zA2, nbr133, tabK2 + 20 * 64, z3,
      sums + 3072, n, gb2);
  // out = bn02(z12) + bn2(z3)
  final_kernel<<<1024, 256, 0, stream>>>((const uint4*)z12, (const uint4*)z3,
                                         out, sums + 2048, bn02_g, bn02_b,
                                         sums + 3072, bn2_g, bn2_b, n);
}

// Round 10
// 69.830 us; speedup vs baseline: 2.8515x; 1.0076x over previous
//
#include <hip/hip_runtime.h>

#define EPS 1e-3f
#define SLOPE 0.01f
#define NBANK 16  // stats atomic spread banks

typedef __attribute__((ext_vector_type(8))) short s8v;
typedef __attribute__((ext_vector_type(4))) float f4v;

union U4S8 {
  uint4 u;
  s8v s;
};

static __device__ inline unsigned f2bf(float x) {  // RNE f32->bf16 (low 16)
  unsigned u = __float_as_uint(x);
  return (u + 0x7fffu + ((u >> 16) & 1u)) >> 16;
}
static __device__ inline float bf_lo(unsigned u) {
  return __uint_as_float(u << 16);
}
static __device__ inline float bf_hi(unsigned u) {
  return __uint_as_float(u & 0xffff0000u);
}

// ---------------------------------------------------------------------------
// prep kernel: fused {feature f32->bf16 convert | sums/zero-row init |
// K1 B-fragment table build}. One dispatch replaces three tiny ones.
// ---------------------------------------------------------------------------
__global__ __launch_bounds__(256) void prep_kernel(
    const float* __restrict__ features, uint4* __restrict__ fbf, int n8,
    const float* __restrict__ w1, const float* __restrict__ w2,
    uint4* __restrict__ tab, float* __restrict__ sums, uint4* __restrict__ r0,
    uint4* __restrict__ r1, uint4* __restrict__ r2, int nc) {
  const int b = blockIdx.x;
  const int tid = threadIdx.x;
  if (b < nc) {  // cvt: features f32 -> bf16 rows
    int i = b * 256 + tid;
    if (i < n8) {
      const float4* p = (const float4*)features + (size_t)i * 2;
      float4 a = p[0], bb = p[1];
      uint4 o;
      o.x = f2bf(a.x) | (f2bf(a.y) << 16);
      o.y = f2bf(a.z) | (f2bf(a.w) << 16);
      o.z = f2bf(bb.x) | (f2bf(bb.y) << 16);
      o.w = f2bf(bb.z) | (f2bf(bb.w) << 16);
      fbf[i] = o;
    }
  } else if (b == nc) {  // init: stats accumulators + zero rows
#pragma unroll
    for (int i = 0; i < 16; i++) sums[i * 256 + tid] = 0.f;
    uint4 z = {0u, 0u, 0u, 0u};
    if (tid < 2) r0[tid] = z;
    else if (tid < 6) r1[tid - 2] = z;
    else if (tid < 10) r2[tid - 6] = z;
  } else if (tid < 64) {  // build K1 tables (20 slot-blocks)
    const int sb = b - nc - 1;  // 0..19
    const int conv = sb / 10, slot = sb % 10;
    const float* w = conv ? w2 : w1;
    const int T = slot >> 1, f = slot & 1;
    const int g = tid >> 4, c = tid & 15;
    s8v t;
#pragma unroll
    for (int j = 0; j < 8; j++) {
      int kl = g * 8 + j;
      int tap = 2 * T + (kl >> 4);
      int ci = kl & 15;
      t[j] = (short)(tap < 9 ? f2bf(w[(tap * 16 + ci) * 32 + 2 * c + f]) : 0);
    }
    U4S8 u;
    u.s = t;
    tab[(conv * 10 + slot) * 64 + tid] = u.u;
  }
}

__global__ __launch_bounds__(64) void build_tab_k2(
    const float* __restrict__ w12, const float* __restrict__ w3,
    const float* __restrict__ sums1, const float* __restrict__ sums2,
    const float* __restrict__ g0, const float* __restrict__ b0,
    const float* __restrict__ g1, const float* __restrict__ b1,
    uint4* __restrict__ tab, int n) {
  __shared__ float stl[64];
  const int conv = blockIdx.x / 20, slot = blockIdx.x % 20;
  const float* w = conv ? w3 : w12;
  const float* sums = conv ? sums2 : sums1;
  const float* bn_g = conv ? g1 : g0;
  const float* bn_b = conv ? b1 : b0;
  const int lane = threadIdx.x;
  if (lane < 32) {
    float ssum = 0.f, qsum = 0.f;
#pragma unroll
    for (int bk = 0; bk < NBANK; bk++) {  // reduce spread banks
      ssum += sums[bk * 64 + lane];
      qsum += sums[bk * 64 + 32 + lane];
    }
    float inv_n = 1.0f / (float)n;
    float m = ssum * inv_n;
    float v = qsum * inv_n - m * m;
    float s = bn_g[lane] * rsqrtf(v + EPS);
    stl[lane] = s;
    stl[32 + lane] = bn_b[lane] - m * s;
  }
  __syncthreads();
  const int g = lane >> 4, c = lane & 15;
  s8v t;
  if (slot < 18) {
    const int k = slot >> 1, f = slot & 1;
#pragma unroll
    for (int j = 0; j < 8; j++) {
      int ci = g * 8 + j;
      t[j] = (short)f2bf(w[(k * 32 + ci) * 32 + 2 * c + f] * stl[ci]);
    }
  } else {
    const int f = slot - 18;
#pragma unroll
    for (int j = 0; j < 8; j++) {
      int kk = g * 8 + j;
      if (kk < 9) {
        float a = 0.f;
        for (int ci = 0; ci < 32; ci++)
          a += stl[32 + ci] * w[(kk * 32 + ci) * 32 + 2 * c + f];
        t[j] = (short)f2bf(a);
      } else {
        t[j] = 0;
      }
    }
  }
  U4S8 u;
  u.s = t;
  tab[(conv * 20 + slot) * 64 + lane] = u.u;
}

// ---------------------------------------------------------------------------
// MFMA subm-conv, R23: R22 structure (verified 70.36us best) with the
// block-amortization lever applied to K1 too: both convs run TPW=8 (half
// the table stagings + block prologues vs TPW=4; same VGPR class, same
// (256,4) occupancy, LDS K1 11.25KB / K2 21.5KB both fit 4/CU). R21's
// lesson stands: no fusion -- separate kernels keep the compiler's
// MLP-friendly allocation (~100 VGPR, 9 gathers in flight).
// Per tile: idx load -> UNCONDITIONAL gathers (dead slots read maintained
// zero row n; static schedule => counted vmcnt) -> slot-skipped MFMAs.
// ---------------------------------------------------------------------------
template <bool PAIRED, int TPWK>
__global__ __launch_bounds__(256, 4) void conv_mfma(
    const unsigned short* __restrict__ src0, const int* __restrict__ nbr0,
    const uint4* __restrict__ tab0, unsigned short* __restrict__ dst0,
    float* __restrict__ osums0, const unsigned short* __restrict__ src1,
    const int* __restrict__ nbr1, const uint4* __restrict__ tab1,
    unsigned short* __restrict__ dst1, float* __restrict__ osums1, int n,
    int gb) {
  constexpr int NS = PAIRED ? 5 : 9;      // mfma slots per tile
  constexpr int NSLOT = PAIRED ? 10 : 20; // table slots
  __shared__ uint4 bwl[NSLOT * 64];
  __shared__ float redl[4 * 64];

  const int tid = threadIdx.x;
  const bool second = (int)blockIdx.x >= gb;
  const unsigned short* src = second ? src1 : src0;
  const int* nbr = second ? nbr1 : nbr0;
  const uint4* tab = second ? tab1 : tab0;
  unsigned short* dst = second ? dst1 : dst0;
  float* osums = second ? osums1 : osums0;

  // stage table global -> LDS (coalesced)
  for (int i = tid; i < NSLOT * 64; i += 256) bwl[i] = tab[i];
  __syncthreads();

  const int lane = tid & 63;
  const int wv = tid >> 6;
  const int g = lane >> 4;  // k-chunk group 0..3
  const int c = lane & 15;  // A row (point) / B col index (cout pair c)

  s8v bbias0, bbias1;
  if (!PAIRED) {
    U4S8 x;
    x.u = bwl[18 * 64 + lane];
    bbias0 = x.s;
    x.u = bwl[19 * 64 + lane];
    bbias1 = x.s;
  }

  const int bid = second ? (int)blockIdx.x - gb : (int)blockIdx.x;
  const int wbase = bid * (64 * TPWK) + wv * (16 * TPWK);

  float s0 = 0.f, s1 = 0.f, q0 = 0.f, q1 = 0.f;  // stats accumulators

#pragma unroll 1
  for (int t = 0; t < TPWK; t++) {
    const int pbase = wbase + t * 16;

    // ---- tile indices (coalesced; per-lane point pbase+c) ----
    int jj[9];
    {
      int pt = pbase + c;
      bool a = pt < n;
#pragma unroll
      for (int k = 0; k < 9; k++) jj[k] = a ? nbr[(size_t)k * n + pt] : -1;
    }

    // ---- UNCONDITIONAL gathers (dead lanes read zero row n: L1-hot line,
    //      broadcast within c-group; static schedule => counted vmcnt) ----
    uint4 ga[NS];
#pragma unroll
    for (int s = 0; s < NS; s++) {
      int jr;
      if (PAIRED) {
        int jA = jj[2 * s];
        int jB = jj[(2 * s + 1 < 9) ? 2 * s + 1 : 8];
        jr = (g & 2) ? jB : jA;
      } else {
        jr = jj[s];
      }
      unsigned jc = jr < 0 ? (unsigned)n : (unsigned)jr;  // zero row
      ga[s] = ((const uint4*)src)[PAIRED ? ((size_t)jc * 2 + (g & 1))
                                         : ((size_t)jc * 4 + g)];
    }

    // ---- per-slot wave-uniform validity (ballot -> scalar MFMA skip) ----
    unsigned vmask = 0;
    if (!PAIRED) {
#pragma unroll
      for (int k = 0; k < 9; k++) vmask |= (jj[k] >= 0 ? 1u : 0u) << k;
    }
    unsigned son = 0;
#pragma unroll
    for (int s = 0; s < NS; s++) {
      bool on;
      if (PAIRED) {
        int jA = jj[2 * s];
        int jB = jj[(2 * s + 1 < 9) ? 2 * s + 1 : 8];
        on = __ballot(jA >= 0 || jB >= 0) != 0ull;
      } else {
        on = __ballot(jj[s] >= 0) != 0ull;
      }
      son |= (on ? 1u : 0u) << s;
    }

    // ---- MFMA accumulate (live slots only) ----
    f4v acc0 = {0.f, 0.f, 0.f, 0.f};
    f4v acc1 = {0.f, 0.f, 0.f, 0.f};
#pragma unroll
    for (int s = 0; s < NS; s++) {
      if (son & (1u << s)) {  // wave-uniform scalar branch
        U4S8 a;
        a.u = ga[s];
        U4S8 b0, b1;
        b0.u = bwl[(s * 2 + 0) * 64 + lane];
        b1.u = bwl[(s * 2 + 1) * 64 + lane];
        acc0 = __builtin_amdgcn_mfma_f32_16x16x32_bf16(a.s, b0.s, acc0, 0, 0, 0);
        acc1 = __builtin_amdgcn_mfma_f32_16x16x32_bf16(a.s, b1.s, acc1, 0, 0, 0);
      }
    }
    if (!PAIRED) {  // bias via validity-matrix MFMA (covers all taps)
      s8v av;
#pragma unroll
      for (int j = 0; j < 8; j++) {
        unsigned kk = (unsigned)(g * 8 + j);
        unsigned bit = (kk < 32u) ? ((vmask >> kk) & 1u) : 0u;
        av[j] = (short)(bit ? 0x3F80 : 0);
      }
      acc0 = __builtin_amdgcn_mfma_f32_16x16x32_bf16(av, bbias0, acc0, 0, 0, 0);
      acc1 = __builtin_amdgcn_mfma_f32_16x16x32_bf16(av, bbias1, acc1, 0, 0, 0);
    }

    // ---- lrelu + stats ----
#pragma unroll
    for (int r = 0; r < 4; r++) {
      float x = acc0[r];
      x = fmaxf(x, SLOPE * x);
      acc0[r] = x;
      s0 += x;
      q0 = fmaf(x, x, q0);
      float y = acc1[r];
      y = fmaxf(y, SLOPE * y);
      acc1[r] = y;
      s1 += y;
      q1 = fmaf(y, y, q1);
    }

    // ---- direct coalesced store: lane (g,c) owns points pbase+g*4+r,
    //      couts (2c,2c+1) -> one packed bf16x2 dword each ----
#pragma unroll
    for (int r = 0; r < 4; r++) {
      int p = pbase + g * 4 + r;
      if (p < n)
        ((unsigned*)dst)[(size_t)p * 16 + c] =
            f2bf(acc0[r]) | (f2bf(acc1[r]) << 16);
    }
  }

  // ---- block stats reduction, one atomic per channel into spread bank ----
  s0 += __shfl_xor(s0, 16, 64);
  s0 += __shfl_xor(s0, 32, 64);
  s1 += __shfl_xor(s1, 16, 64);
  s1 += __shfl_xor(s1, 32, 64);
  q0 += __shfl_xor(q0, 16, 64);
  q0 += __shfl_xor(q0, 32, 64);
  q1 += __shfl_xor(q1, 16, 64);
  q1 += __shfl_xor(q1, 32, 64);
  if (lane < 16) {
    redl[wv * 64 + 2 * c] = s0;
    redl[wv * 64 + 2 * c + 1] = s1;
    redl[wv * 64 + 32 + 2 * c] = q0;
    redl[wv * 64 + 32 + 2 * c + 1] = q1;
  }
  __syncthreads();
  if (tid < 64) {
    float t = redl[tid] + redl[64 + tid] + redl[128 + tid] + redl[192 + tid];
    atomicAdd(&osums[(bid & (NBANK - 1)) * 64 + tid], t);
  }
}

// out = bnA(z12) + bnB(z3), both inputs bf16 [n][32]; sums are NBANK-spread
__global__ __launch_bounds__(256) void final_kernel(
    const uint4* __restrict__ z12, const uint4* __restrict__ z3,
    float* __restrict__ out, const float* __restrict__ sumsA,
    const float* __restrict__ gA, const float* __restrict__ bA,
    const float* __restrict__ sumsB, const float* __restrict__ gB,
    const float* __restrict__ bB, int n) {
  __shared__ float st[128];  // sA tA sB tB
  const int tid = threadIdx.x;
  if (tid < 32) {
    float sa = 0.f, qa = 0.f, sb = 0.f, qb = 0.f;
#pragma unroll
    for (int bk = 0; bk < NBANK; bk++) {
      sa += sumsA[bk * 64 + tid];
      qa += sumsA[bk * 64 + 32 + tid];
      sb += sumsB[bk * 64 + tid];
      qb += sumsB[bk * 64 + 32 + tid];
    }
    float inv_n = 1.0f / (float)n;
    float m = sa * inv_n;
    float v = qa * inv_n - m * m;
    float s = gA[tid] * rsqrtf(v + EPS);
    st[tid] = s;
    st[32 + tid] = bA[tid] - m * s;
    m = sb * inv_n;
    v = qb * inv_n - m * m;
    s = gB[tid] * rsqrtf(v + EPS);
    st[64 + tid] = s;
    st[96 + tid] = bB[tid] - m * s;
  }
  __syncthreads();
  const int total = n * 4;  // 8-channel chunks
  for (int i = blockIdx.x * 256 + tid; i < total; i += gridDim.x * 256) {
    int c0 = (i & 3) * 8;
    uint4 a = z12[i], b = z3[i];
    float4 r0, r1;
    r0.x = bf_lo(a.x) * st[c0 + 0] + st[32 + c0 + 0] + bf_lo(b.x) * st[64 + c0 + 0] + st[96 + c0 + 0];
    r0.y = bf_hi(a.x) * st[c0 + 1] + st[32 + c0 + 1] + bf_hi(b.x) * st[64 + c0 + 1] + st[96 + c0 + 1];
    r0.z = bf_lo(a.y) * st[c0 + 2] + st[32 + c0 + 2] + bf_lo(b.y) * st[64 + c0 + 2] + st[96 + c0 + 2];
    r0.w = bf_hi(a.y) * st[c0 + 3] + st[32 + c0 + 3] + bf_hi(b.y) * st[64 + c0 + 3] + st[96 + c0 + 3];
    r1.x = bf_lo(a.z) * st[c0 + 4] + st[32 + c0 + 4] + bf_lo(b.z) * st[64 + c0 + 4] + st[96 + c0 + 4];
    r1.y = bf_hi(a.z) * st[c0 + 5] + st[32 + c0 + 5] + bf_hi(b.z) * st[64 + c0 + 5] + st[96 + c0 + 5];
    r1.z = bf_lo(a.w) * st[c0 + 6] + st[32 + c0 + 6] + bf_lo(b.w) * st[64 + c0 + 6] + st[96 + c0 + 6];
    r1.w = bf_hi(a.w) * st[c0 + 7] + st[32 + c0 + 7] + bf_hi(b.w) * st[64 + c0 + 7] + st[96 + c0 + 7];
    ((float4*)out)[2 * i + 0] = r0;
    ((float4*)out)[2 * i + 1] = r1;
  }
}

extern "C" void kernel_launch(void* const* d_in, const int* in_sizes, int n_in,
                              void* d_out, int out_size, void* d_ws,
                              size_t ws_size, hipStream_t stream) {
  const float* features = (const float*)d_in[0];
  const int* nbr133 = (const int*)d_in[1];
  const int* nbr313 = (const int*)d_in[2];
  const float* conv1_w = (const float*)d_in[3];
  const float* conv12_w = (const float*)d_in[4];
  const float* conv2_w = (const float*)d_in[5];
  const float* conv3_w = (const float*)d_in[6];
  const float* bn0_g = (const float*)d_in[7];
  const float* bn0_b = (const float*)d_in[8];
  const float* bn02_g = (const float*)d_in[9];
  const float* bn02_b = (const float*)d_in[10];
  const float* bn1_g = (const float*)d_in[11];
  const float* bn1_b = (const float*)d_in[12];
  const float* bn2_g = (const float*)d_in[13];
  const float* bn2_b = (const float*)d_in[14];
  float* out = (float*)d_out;

  const int n = in_sizes[0] / 16;  // 250000
  char* ws = (char*)d_ws;
  const size_t A = (size_t)n * 64 + 64;  // bf16 [n+1][32] region

  // region0: fbf ([n+1][16] bf16) overlaid later by z12 ([n][32] bf16)
  unsigned short* fbf = (unsigned short*)ws;
  unsigned short* z12 = (unsigned short*)ws;
  unsigned short* zA1 = (unsigned short*)(ws + A);
  unsigned short* zA2 = (unsigned short*)(ws + 2 * A);
  unsigned short* z3 = (unsigned short*)(ws + 3 * A);
  float* sums = (float*)(ws + 4 * A);
  // sums: 4 stat sets x NBANK banks x 64 floats:
  //   +0 z1 | +1024 z2 | +2048 z12 | +3072 z3
  uint4* tabK1 = (uint4*)(ws + 4 * A + 4 * NBANK * 64 * 4);
  uint4* tabK2 = tabK1 + 20 * 64;

  const int n8 = n * 2;  // 8-float chunks of features
  const int nc = (n8 + 255) / 256;
  // fused prep: cvt | init | tabK1 build
  prep_kernel<<<nc + 21, 256, 0, stream>>>(
      features, (uint4*)fbf, n8, conv1_w, conv2_w, tabK1, sums,
      (uint4*)(ws + (size_t)n * 32),            // fbf row n
      (uint4*)(ws + A + (size_t)n * 64),        // zA1 row n
      (uint4*)(ws + 2 * A + (size_t)n * 64),    // zA2 row n
      nc);

  const int gb = (n + 511) / 512;  // TPW=8: 512 pts/block (both convs)
  // K1: conv1 (fbf,nbr133)->zA1 || conv2 (fbf,nbr313)->zA2
  conv_mfma<true, 8><<<2 * gb, 256, 0, stream>>>(
      fbf, nbr133, tabK1, zA1, sums + 0, fbf, nbr313, tabK1 + 10 * 64, zA2,
      sums + 1024, n, gb);
  // tables for K2 (BN of K1 folded in; needs K1 stats)
  build_tab_k2<<<40, 64, 0, stream>>>(conv12_w, conv3_w, sums + 0, sums + 1024,
                                      bn0_g, bn0_b, bn1_g, bn1_b, tabK2, n);
  // K2: conv12 (bn0(zA1),nbr313)->z12 || conv3 (bn1(zA2),nbr133)->z3
  conv_mfma<false, 8><<<2 * gb, 256, 0, stream>>>(
      zA1, nbr313, tabK2, z12, sums + 2048, zA2, nbr133, tabK2 + 20 * 64, z3,
      sums + 3072, n, gb);
  // out = bn02(z12) + bn2(z3)
  final_kernel<<<1024, 256, 0, stream>>>((const uint4*)z12, (const uint4*)z3,
                                         out, sums + 2048, bn02_g, bn02_b,
                                         sums + 3072, bn2_g, bn2_b, n);
}